// Round 5
// baseline (393.132 us; speedup 1.0000x reference)
//
#include <hip/hip_runtime.h>
#include <hip/hip_bf16.h>
#include <cstdint>
#include <cstddef>

// BaseNet fused: B=262144 samples, d=512.
// H = relu(reshape(combined,[2B,512]) @ W_in + b_in)   [2B,128]
// m[s] = 0.5*(H[2s]+H[2s+1])                           [B,128]
// g1 = relu(m @ W1 + b1); g2 = relu(g1 @ W2 + b2)      [B,128],[B,64]
// out = sigmoid(g2 . (W_out[:64]+W_out[64:]) + b_out)  [B]
// Single fused GEMM kernel: the wave that computes 32 H-rows owns those 16
// samples end-to-end (no global M roundtrip). W1/W2 fragments stream from L2.

#define NROWS   524288   // 2B
#define NSAMP   262144   // B

typedef __attribute__((ext_vector_type(8))) short  bf16x8;
typedef __attribute__((ext_vector_type(4))) float  f32x4;

__device__ __forceinline__ unsigned short f2bf(float f) {
    unsigned u = __float_as_uint(f);
    u += 0x7fffu + ((u >> 16) & 1u);   // round-to-nearest-even
    return (unsigned short)(u >> 16);
}

// packed bf16 convert: 4x v_cvt_pk_bf16_f32 (RNE, same numerics as f2bf)
__device__ __forceinline__ bf16x8 cvt8(f32x4 lo, f32x4 hi) {
    union { unsigned u[4]; bf16x8 v; } r;
    asm("v_cvt_pk_bf16_f32 %0, %1, %2" : "=v"(r.u[0]) : "v"(lo[0]), "v"(lo[1]));
    asm("v_cvt_pk_bf16_f32 %0, %1, %2" : "=v"(r.u[1]) : "v"(lo[2]), "v"(lo[3]));
    asm("v_cvt_pk_bf16_f32 %0, %1, %2" : "=v"(r.u[2]) : "v"(hi[0]), "v"(hi[1]));
    asm("v_cvt_pk_bf16_f32 %0, %1, %2" : "=v"(r.u[3]) : "v"(hi[2]), "v"(hi[3]));
    return r.v;
}

// ---------------- workspace layout (bytes) ----------------
#define WS_WIN   0          // Win frags: 16*8*64*8 bf16 = 131072 B
#define WS_W1    131072     // W1 frags:  4*8*64*8 bf16 = 32768 B
#define WS_W2    163840     // W2 frags:  4*4*64*8 bf16 = 16384 B
#define WS_WEFF  180224     // 64 floats

// ---------------- prep: pack weights to MFMA B-fragment layout ----------------
// Standard B-frag (16x16x32): lane l holds B[k=(l>>4)*8+j][col=l&15], j=0..7.
// fWin uses a PERMUTED k mapping to match kA's coalesced A loads:
//   slot j of lane (lg=l>>4) holds k = (j<4) ? lg*4+j : 16+lg*4+(j-4)  (within 32-group)
__global__ void prep_kernel(const float* __restrict__ W_in,
                            const float* __restrict__ W1,
                            const float* __restrict__ W2,
                            const float* __restrict__ W_out,
                            unsigned short* __restrict__ fWin,
                            unsigned short* __restrict__ fW1,
                            unsigned short* __restrict__ fW2,
                            float* __restrict__ weff) {
    int tid = blockIdx.x * 256 + threadIdx.x;
    if (tid < 65536) {                       // W_in [512][128]: KT=16, NT=8 (permuted k)
        int e = tid;
        int j = e & 7, l = (e >> 3) & 63, rest = e >> 9;
        int n = rest & 7, kt = rest >> 3;
        int lg = l >> 4;
        int kin = (j < 4) ? (lg * 4 + j) : (16 + lg * 4 + (j - 4));
        int k = kt * 32 + kin;
        int col = n * 16 + (l & 15);
        fWin[e] = f2bf(W_in[k * 128 + col]);
    } else if (tid < 65536 + 16384) {        // W1 [128][128]: KT=4, NT=8 (standard)
        int e = tid - 65536;
        int j = e & 7, l = (e >> 3) & 63, rest = e >> 9;
        int n = rest & 7, kt = rest >> 3;
        int k = kt * 32 + ((l >> 4) << 3) + j;
        int col = n * 16 + (l & 15);
        fW1[e] = f2bf(W1[k * 128 + col]);
    } else if (tid < 65536 + 16384 + 8192) { // W2 [128][64]: KT=4, NT=4 (standard)
        int e = tid - 65536 - 16384;
        int j = e & 7, l = (e >> 3) & 63, rest = e >> 9;
        int n = rest & 3, kt = rest >> 2;
        int k = kt * 32 + ((l >> 4) << 3) + j;
        int col = n * 16 + (l & 15);
        fW2[e] = f2bf(W2[k * 64 + col]);
    } else if (tid < 65536 + 16384 + 8192 + 64) {
        int c = tid - (65536 + 16384 + 8192);
        weff[c] = W_out[c] + W_out[64 + c];
    }
}

// ---------------- fused kernel: GEMM + GCN layers + sigmoid -> out ----------
// 256 persistent blocks (1/CU: 160KB LDS exactly — AITER precedent), 512
// threads = 8 waves (2/EU), waves_per_eu(2,2) pins VGPR budget at 256.
// Main GEMM: permuted-k A loads (16 rows x 64B contiguous per instr),
// 4-deep register staging, prefetch distance 2; chunks 6,7 prefetch the
// NEXT tile (phase-aligned: 8 % 4 == 0) so the fused epilogue hides under
// HBM latency. Epilogue: m -> XOR-swizzled per-wave LDS bounce -> layers
// 2-4 via MFMA with W1/W2 frags streamed from L2 -> sigmoid -> out.
__global__ void __launch_bounds__(512) __attribute__((amdgpu_waves_per_eu(2, 2)))
kA(const float* __restrict__ A,              // [2B][512] fp32 (= combined)
   const unsigned short* __restrict__ fWin,  // frag layout (permuted k)
   const unsigned short* __restrict__ fW1,   // frag layout (standard)
   const unsigned short* __restrict__ fW2,   // frag layout (standard)
   const float* __restrict__ weff,
   const float* __restrict__ b_in,
   const float* __restrict__ b1,
   const float* __restrict__ b2,
   const float* __restrict__ b_out,
   float* __restrict__ out) {                // [B] fp32
    __shared__ __align__(16) unsigned short lds[81920];  // 163840 B = 160 KB
    unsigned short* lwin = lds;                          // 131072 B: W_in frags
    {
        const f32x4* src = (const f32x4*)fWin;
        f32x4* dst = (f32x4*)lds;
        int tid = threadIdx.x;
        #pragma unroll
        for (int i = 0; i < 16; ++i) dst[i * 512 + tid] = src[i * 512 + tid];
    }
    __syncthreads();
    const int w = threadIdx.x >> 6, l = threadIdx.x & 63;
    const int lr = l & 15, lg = l >> 4;
    unsigned short* bw = lds + 65536 + w * 2048;         // per-wave 4KB bounce
    float binv[8], b1v[8], b2v[4], wev[4];
    #pragma unroll
    for (int n = 0; n < 8; ++n) { binv[n] = b_in[n * 16 + lr]; b1v[n] = b1[n * 16 + lr]; }
    #pragma unroll
    for (int n = 0; n < 4; ++n) { b2v[n] = b2[n * 16 + lr]; wev[n] = weff[n * 16 + lr]; }
    const float bo = b_out[0];

    const size_t TSTR = (size_t)65536 * 512;   // next-tile float offset (t += 256)
    const float* a0 = A + ((size_t)blockIdx.x * 256 + (size_t)w * 32 + lr) * 512 + lg * 4;
    const float* a1 = a0 + (size_t)16 * 512;

    // 4-deep register staging: [buf][rowtile][ks][half]
    f32x4 st[4][2][2][2];
    #pragma unroll
    for (int pc = 0; pc < 2; ++pc) {
        #pragma unroll
        for (int ks = 0; ks < 2; ++ks) {
            st[pc][0][ks][0] = *(const f32x4*)(a0 + pc * 64 + ks * 32);
            st[pc][0][ks][1] = *(const f32x4*)(a0 + pc * 64 + ks * 32 + 16);
            st[pc][1][ks][0] = *(const f32x4*)(a1 + pc * 64 + ks * 32);
            st[pc][1][ks][1] = *(const f32x4*)(a1 + pc * 64 + ks * 32 + 16);
        }
    }

    for (int i = 0; i < 8; ++i) {            // 8 tiles per block
        const size_t nextoff = (i == 7) ? 0 : TSTR;
        f32x4 acc[2][8];
        #pragma unroll
        for (int rt = 0; rt < 2; ++rt)
            #pragma unroll
            for (int n = 0; n < 8; ++n) acc[rt][n] = (f32x4){0.f, 0.f, 0.f, 0.f};

        #pragma unroll
        for (int c = 0; c < 8; ++c) {        // 8 chunks x 64 floats
            const int cb = c & 3;
            {   // prefetch chunk c+2 (chunks 6,7 target the next tile)
                const int nb = (c + 2) & 3;
                const float* q0 = (c < 6) ? (a0 + (c + 2) * 64) : (a0 + nextoff + (c - 6) * 64);
                const float* q1 = q0 + (size_t)16 * 512;
                #pragma unroll
                for (int ks = 0; ks < 2; ++ks) {
                    st[nb][0][ks][0] = *(const f32x4*)(q0 + ks * 32);
                    st[nb][0][ks][1] = *(const f32x4*)(q0 + ks * 32 + 16);
                    st[nb][1][ks][0] = *(const f32x4*)(q1 + ks * 32);
                    st[nb][1][ks][1] = *(const f32x4*)(q1 + ks * 32 + 16);
                }
            }
            #pragma unroll
            for (int ks = 0; ks < 2; ++ks) {
                const int kg = c * 2 + ks;
                bf16x8 af0 = cvt8(st[cb][0][ks][0], st[cb][0][ks][1]);
                bf16x8 af1 = cvt8(st[cb][1][ks][0], st[cb][1][ks][1]);
                #pragma unroll
                for (int n = 0; n < 8; ++n) {
                    bf16x8 bf = *(const bf16x8*)&lwin[((kg * 8 + n) * 64 + l) * 8];
                    acc[0][n] = __builtin_amdgcn_mfma_f32_16x16x32_bf16(af0, bf, acc[0][n], 0, 0, 0);
                    acc[1][n] = __builtin_amdgcn_mfma_f32_16x16x32_bf16(af1, bf, acc[1][n], 0, 0, 0);
                }
            }
        }

        // ---- epilogue: bias+relu+pair-mean -> bounce [16][128] bf16, XOR-swz.
        // C layout: row=(l>>4)*4+r, col=l&15; rows 2s,2s+1 pair to sample s.
        // rt=0 -> samples 0..7 (rows 0..7), rt=1 -> samples 8..15.
        #pragma unroll
        for (int rt = 0; rt < 2; ++rt) {
            #pragma unroll
            for (int n = 0; n < 8; ++n) {
                const float b = binv[n];
                float h0 = fmaxf(acc[rt][n][0] + b, 0.f);
                float h1 = fmaxf(acc[rt][n][1] + b, 0.f);
                float h2 = fmaxf(acc[rt][n][2] + b, 0.f);
                float h3 = fmaxf(acc[rt][n][3] + b, 0.f);
                int row0 = rt * 8 + 2 * lg, row1 = row0 + 1;
                int col2 = (n * 16 + lr) * 2;
                *(unsigned short*)((char*)bw + row0 * 256 + (col2 ^ ((row0 & 7) << 4))) = f2bf(0.5f * (h0 + h1));
                *(unsigned short*)((char*)bw + row1 * 256 + (col2 ^ ((row1 & 7) << 4))) = f2bf(0.5f * (h2 + h3));
            }
        }
        asm volatile("s_waitcnt lgkmcnt(0)" ::: "memory");

        // ---- layer 2: g1 = relu(m @ W1 + b1), A-frags from bounce ----
        bf16x8 a2[4];
        #pragma unroll
        for (int ks = 0; ks < 4; ++ks) {
            int roff = lr * 256 + ((ks * 64 + lg * 16) ^ ((lr & 7) << 4));
            a2[ks] = *(const bf16x8*)((const char*)bw + roff);
        }
        f32x4 acc1[8];
        #pragma unroll
        for (int n = 0; n < 8; ++n) acc1[n] = (f32x4){0.f, 0.f, 0.f, 0.f};
        #pragma unroll
        for (int ks = 0; ks < 4; ++ks) {
            #pragma unroll
            for (int n = 0; n < 8; ++n) {
                bf16x8 bfw = *(const bf16x8*)&fW1[(size_t)((ks * 8 + n) * 64 + l) * 8];
                acc1[n] = __builtin_amdgcn_mfma_f32_16x16x32_bf16(a2[ks], bfw, acc1[n], 0, 0, 0);
            }
        }
        // g1 -> bounce (overwrite; data-dep on a2 orders writes after reads)
        #pragma unroll
        for (int n = 0; n < 8; ++n) {
            #pragma unroll
            for (int r = 0; r < 4; ++r) {
                float g = fmaxf(acc1[n][r] + b1v[n], 0.f);
                int row = lg * 4 + r;
                int col2 = (n * 16 + lr) * 2;
                *(unsigned short*)((char*)bw + row * 256 + (col2 ^ ((row & 7) << 4))) = f2bf(g);
            }
        }
        asm volatile("s_waitcnt lgkmcnt(0)" ::: "memory");

        // ---- layer 3: g2 = relu(g1 @ W2 + b2) ----
        bf16x8 a3[4];
        #pragma unroll
        for (int ks = 0; ks < 4; ++ks) {
            int roff = lr * 256 + ((ks * 64 + lg * 16) ^ ((lr & 7) << 4));
            a3[ks] = *(const bf16x8*)((const char*)bw + roff);
        }
        f32x4 acc2[4];
        #pragma unroll
        for (int n = 0; n < 4; ++n) acc2[n] = (f32x4){0.f, 0.f, 0.f, 0.f};
        #pragma unroll
        for (int ks = 0; ks < 4; ++ks) {
            #pragma unroll
            for (int n = 0; n < 4; ++n) {
                bf16x8 bfw = *(const bf16x8*)&fW2[(size_t)((ks * 4 + n) * 64 + l) * 8];
                acc2[n] = __builtin_amdgcn_mfma_f32_16x16x32_bf16(a3[ks], bfw, acc2[n], 0, 0, 0);
            }
        }

        // ---- layer 4: dot w_eff, 16-lane reduce, sigmoid, store ----
        float p0 = 0.f, p1 = 0.f, p2 = 0.f, p3 = 0.f;
        #pragma unroll
        for (int n = 0; n < 4; ++n) {
            p0 += fmaxf(acc2[n][0] + b2v[n], 0.f) * wev[n];
            p1 += fmaxf(acc2[n][1] + b2v[n], 0.f) * wev[n];
            p2 += fmaxf(acc2[n][2] + b2v[n], 0.f) * wev[n];
            p3 += fmaxf(acc2[n][3] + b2v[n], 0.f) * wev[n];
        }
        #pragma unroll
        for (int m = 1; m < 16; m <<= 1) {
            p0 += __shfl_xor(p0, m);
            p1 += __shfl_xor(p1, m);
            p2 += __shfl_xor(p2, m);
            p3 += __shfl_xor(p3, m);
        }
        const size_t t = (size_t)blockIdx.x + (size_t)i * 256;
        const size_t s0 = t * 128 + (size_t)w * 16;
        float s0f = 1.f / (1.f + expf(-(p0 + bo)));
        float s1f = 1.f / (1.f + expf(-(p1 + bo)));
        float s2f = 1.f / (1.f + expf(-(p2 + bo)));
        float s3f = 1.f / (1.f + expf(-(p3 + bo)));
        if (lr < 4) {
            float v = (lr == 0) ? s0f : (lr == 1) ? s1f : (lr == 2) ? s2f : s3f;
            out[s0 + lg * 4 + lr] = v;
        }

        a0 += nextoff;
        a1 += nextoff;
    }
}

// ---------------- host launcher ----------------
extern "C" void kernel_launch(void* const* d_in, const int* in_sizes, int n_in,
                              void* d_out, int out_size, void* d_ws, size_t ws_size,
                              hipStream_t stream) {
    const float* combined = (const float*)d_in[0];
    const float* W_in  = (const float*)d_in[1];
    const float* b_in  = (const float*)d_in[2];
    const float* W1    = (const float*)d_in[3];
    const float* b1    = (const float*)d_in[4];
    const float* W2    = (const float*)d_in[5];
    const float* b2    = (const float*)d_in[6];
    const float* W_out = (const float*)d_in[7];
    const float* b_out = (const float*)d_in[8];
    float* out = (float*)d_out;

    char* ws = (char*)d_ws;
    unsigned short* fWin = (unsigned short*)(ws + WS_WIN);
    unsigned short* fW1  = (unsigned short*)(ws + WS_W1);
    unsigned short* fW2  = (unsigned short*)(ws + WS_W2);
    float* weff          = (float*)(ws + WS_WEFF);

    prep_kernel<<<(65536 + 16384 + 8192 + 64 + 255) / 256, 256, 0, stream>>>(
        W_in, W1, W2, W_out, fWin, fW1, fW2, weff);
    kA<<<256, 512, 0, stream>>>(combined, fWin, fW1, fW2, weff,
                                b_in, b1, b2, b_out, out);
}

// Round 6
// 290.306 us; speedup vs baseline: 1.3542x; 1.3542x over previous
//
#include <hip/hip_runtime.h>
#include <hip/hip_bf16.h>
#include <cstdint>
#include <cstddef>

// BaseNet fused: B=262144 samples, d=512.
// H = relu(reshape(combined,[2B,512]) @ W_in + b_in)   [2B,128]
// m[s] = 0.5*(H[2s]+H[2s+1])                           [B,128]
// g1 = relu(m @ W1 + b1); g2 = relu(g1 @ W2 + b2)      [B,128],[B,64]
// out = sigmoid(g2 . (W_out[:64]+W_out[64:]) + b_out)  [B]
// Single fused kernel: the wave that computes 32 H-rows owns those 16 samples
// end-to-end (no global M roundtrip). W1/W2 fragments stream from L2.
// Round-6: staging ring shrunk to 64 VGPR (round-5 spilled at 128).

#define NROWS   524288   // 2B
#define NSAMP   262144   // B

typedef __attribute__((ext_vector_type(8))) short  bf16x8;
typedef __attribute__((ext_vector_type(4))) float  f32x4;

__device__ __forceinline__ unsigned short f2bf(float f) {
    unsigned u = __float_as_uint(f);
    u += 0x7fffu + ((u >> 16) & 1u);   // round-to-nearest-even
    return (unsigned short)(u >> 16);
}

// packed bf16 convert: 4x v_cvt_pk_bf16_f32 (RNE, same numerics as f2bf)
__device__ __forceinline__ bf16x8 cvt8(f32x4 lo, f32x4 hi) {
    union { unsigned u[4]; bf16x8 v; } r;
    asm("v_cvt_pk_bf16_f32 %0, %1, %2" : "=v"(r.u[0]) : "v"(lo[0]), "v"(lo[1]));
    asm("v_cvt_pk_bf16_f32 %0, %1, %2" : "=v"(r.u[1]) : "v"(lo[2]), "v"(lo[3]));
    asm("v_cvt_pk_bf16_f32 %0, %1, %2" : "=v"(r.u[2]) : "v"(hi[0]), "v"(hi[1]));
    asm("v_cvt_pk_bf16_f32 %0, %1, %2" : "=v"(r.u[3]) : "v"(hi[2]), "v"(hi[3]));
    return r.v;
}

// ---------------- workspace layout (bytes) ----------------
#define WS_WIN   0          // Win frags: 16*8*64*8 bf16 = 131072 B
#define WS_W1    131072     // W1 frags:  4*8*64*8 bf16 = 32768 B
#define WS_W2    163840     // W2 frags:  4*4*64*8 bf16 = 16384 B
#define WS_WEFF  180224     // 64 floats

// ---------------- prep: pack weights to MFMA B-fragment layout ----------------
// Standard B-frag (16x16x32): lane l holds B[k=(l>>4)*8+j][col=l&15], j=0..7.
// fWin uses a PERMUTED k mapping to match kA's coalesced A loads:
//   slot j of lane (lg=l>>4) holds k = (j<4) ? lg*4+j : 16+lg*4+(j-4)  (within 32-group)
__global__ void prep_kernel(const float* __restrict__ W_in,
                            const float* __restrict__ W1,
                            const float* __restrict__ W2,
                            const float* __restrict__ W_out,
                            unsigned short* __restrict__ fWin,
                            unsigned short* __restrict__ fW1,
                            unsigned short* __restrict__ fW2,
                            float* __restrict__ weff) {
    int tid = blockIdx.x * 256 + threadIdx.x;
    if (tid < 65536) {                       // W_in [512][128]: KT=16, NT=8 (permuted k)
        int e = tid;
        int j = e & 7, l = (e >> 3) & 63, rest = e >> 9;
        int n = rest & 7, kt = rest >> 3;
        int lg = l >> 4;
        int kin = (j < 4) ? (lg * 4 + j) : (16 + lg * 4 + (j - 4));
        int k = kt * 32 + kin;
        int col = n * 16 + (l & 15);
        fWin[e] = f2bf(W_in[k * 128 + col]);
    } else if (tid < 65536 + 16384) {        // W1 [128][128]: KT=4, NT=8 (standard)
        int e = tid - 65536;
        int j = e & 7, l = (e >> 3) & 63, rest = e >> 9;
        int n = rest & 7, kt = rest >> 3;
        int k = kt * 32 + ((l >> 4) << 3) + j;
        int col = n * 16 + (l & 15);
        fW1[e] = f2bf(W1[k * 128 + col]);
    } else if (tid < 65536 + 16384 + 8192) { // W2 [128][64]: KT=4, NT=4 (standard)
        int e = tid - 65536 - 16384;
        int j = e & 7, l = (e >> 3) & 63, rest = e >> 9;
        int n = rest & 3, kt = rest >> 2;
        int k = kt * 32 + ((l >> 4) << 3) + j;
        int col = n * 16 + (l & 15);
        fW2[e] = f2bf(W2[k * 64 + col]);
    } else if (tid < 65536 + 16384 + 8192 + 64) {
        int c = tid - (65536 + 16384 + 8192);
        weff[c] = W_out[c] + W_out[64 + c];
    }
}

// ---------------- fused kernel: GEMM + GCN layers + sigmoid -> out ----------
// 256 persistent blocks (1/CU, 160KB LDS), 512 threads = 8 waves (2/EU),
// waves_per_eu(2,2) pins the VGPR budget at 256.
// Main GEMM: permuted-k A loads (16 rows x 64B contiguous per instr).
// Staging: 32-float chunks, ring of 4 (st[4][2][2] = 64 VGPR), prefetch
// distance 3 -> 12 outstanding 1KB loads/wave (96KB/CU in flight) so the
// fused epilogue stays memory-covered. 16 chunks/tile, 16%4==0: chunks
// 13..15 prefetch the NEXT tile's chunks 0..2 phase-aligned.
// Epilogue: m -> XOR-swizzled per-wave LDS bounce -> layers 2-4 via MFMA
// with W1/W2 frags streamed from L2 -> sigmoid -> out.
__global__ void __launch_bounds__(512) __attribute__((amdgpu_waves_per_eu(2, 2)))
kA(const float* __restrict__ A,              // [2B][512] fp32 (= combined)
   const unsigned short* __restrict__ fWin,  // frag layout (permuted k)
   const unsigned short* __restrict__ fW1,   // frag layout (standard)
   const unsigned short* __restrict__ fW2,   // frag layout (standard)
   const float* __restrict__ weff,
   const float* __restrict__ b_in,
   const float* __restrict__ b1,
   const float* __restrict__ b2,
   const float* __restrict__ b_out,
   float* __restrict__ out) {                // [B] fp32
    __shared__ __align__(16) unsigned short lds[81920];  // 163840 B = 160 KB
    unsigned short* lwin = lds;                          // 131072 B: W_in frags
    {
        const f32x4* src = (const f32x4*)fWin;
        f32x4* dst = (f32x4*)lds;
        int tid = threadIdx.x;
        #pragma unroll
        for (int i = 0; i < 16; ++i) dst[i * 512 + tid] = src[i * 512 + tid];
    }
    __syncthreads();
    const int w = threadIdx.x >> 6, l = threadIdx.x & 63;
    const int lr = l & 15, lg = l >> 4;
    unsigned short* bw = lds + 65536 + w * 2048;         // per-wave 4KB bounce
    float binv[8], b1v[8], b2v[4], wev[4];
    #pragma unroll
    for (int n = 0; n < 8; ++n) { binv[n] = b_in[n * 16 + lr]; b1v[n] = b1[n * 16 + lr]; }
    #pragma unroll
    for (int n = 0; n < 4; ++n) { b2v[n] = b2[n * 16 + lr]; wev[n] = weff[n * 16 + lr]; }
    const float bo = b_out[0];

    const size_t TSTR = (size_t)65536 * 512;   // next-tile float offset (t += 256)
    const float* a0 = A + ((size_t)blockIdx.x * 256 + (size_t)w * 32 + lr) * 512 + lg * 4;
    const float* a1 = a0 + (size_t)16 * 512;

    // staging ring: [buf][rowtile][half], chunk = 32 floats (1 k-group)
    f32x4 st[4][2][2];
    #pragma unroll
    for (int pc = 0; pc < 3; ++pc) {
        st[pc][0][0] = *(const f32x4*)(a0 + pc * 32);
        st[pc][0][1] = *(const f32x4*)(a0 + pc * 32 + 16);
        st[pc][1][0] = *(const f32x4*)(a1 + pc * 32);
        st[pc][1][1] = *(const f32x4*)(a1 + pc * 32 + 16);
    }

    for (int i = 0; i < 8; ++i) {            // 8 tiles per block
        const size_t nextoff = (i == 7) ? 0 : TSTR;
        f32x4 acc[2][8];
        #pragma unroll
        for (int rt = 0; rt < 2; ++rt)
            #pragma unroll
            for (int n = 0; n < 8; ++n) acc[rt][n] = (f32x4){0.f, 0.f, 0.f, 0.f};

        #pragma unroll
        for (int c = 0; c < 16; ++c) {       // 16 chunks x 32 floats
            {   // prefetch chunk c+3 (chunks 13..15 target the next tile)
                const int nb = (c + 3) & 3;
                const float* q0 = (c < 13) ? (a0 + (c + 3) * 32)
                                           : (a0 + nextoff + (c - 13) * 32);
                const float* q1 = q0 + (size_t)16 * 512;
                st[nb][0][0] = *(const f32x4*)(q0);
                st[nb][0][1] = *(const f32x4*)(q0 + 16);
                st[nb][1][0] = *(const f32x4*)(q1);
                st[nb][1][1] = *(const f32x4*)(q1 + 16);
            }
            const int cb = c & 3;
            bf16x8 af0 = cvt8(st[cb][0][0], st[cb][0][1]);
            bf16x8 af1 = cvt8(st[cb][1][0], st[cb][1][1]);
            #pragma unroll
            for (int n = 0; n < 8; ++n) {
                bf16x8 bf = *(const bf16x8*)&lwin[((c * 8 + n) * 64 + l) * 8];
                acc[0][n] = __builtin_amdgcn_mfma_f32_16x16x32_bf16(af0, bf, acc[0][n], 0, 0, 0);
                acc[1][n] = __builtin_amdgcn_mfma_f32_16x16x32_bf16(af1, bf, acc[1][n], 0, 0, 0);
            }
        }

        // ---- epilogue: bias+relu+pair-mean -> bounce [16][128] bf16, XOR-swz.
        // C layout: row=(l>>4)*4+r, col=l&15; rows 2s,2s+1 pair to sample s.
        #pragma unroll
        for (int rt = 0; rt < 2; ++rt) {
            #pragma unroll
            for (int n = 0; n < 8; ++n) {
                const float b = binv[n];
                float h0 = fmaxf(acc[rt][n][0] + b, 0.f);
                float h1 = fmaxf(acc[rt][n][1] + b, 0.f);
                float h2 = fmaxf(acc[rt][n][2] + b, 0.f);
                float h3 = fmaxf(acc[rt][n][3] + b, 0.f);
                int row0 = rt * 8 + 2 * lg, row1 = row0 + 1;
                int col2 = (n * 16 + lr) * 2;
                *(unsigned short*)((char*)bw + row0 * 256 + (col2 ^ ((row0 & 7) << 4))) = f2bf(0.5f * (h0 + h1));
                *(unsigned short*)((char*)bw + row1 * 256 + (col2 ^ ((row1 & 7) << 4))) = f2bf(0.5f * (h2 + h3));
            }
        }
        __builtin_amdgcn_s_waitcnt(0xc07f);  // lgkmcnt(0): m-bounce visible

        // ---- layer 2: g1 = relu(m @ W1 + b1), A-frags from bounce ----
        bf16x8 a2[4];
        #pragma unroll
        for (int ks = 0; ks < 4; ++ks) {
            int roff = lr * 256 + ((ks * 64 + lg * 16) ^ ((lr & 7) << 4));
            a2[ks] = *(const bf16x8*)((const char*)bw + roff);
        }
        f32x4 acc1[8];
        #pragma unroll
        for (int n = 0; n < 8; ++n) acc1[n] = (f32x4){0.f, 0.f, 0.f, 0.f};
        #pragma unroll
        for (int ks = 0; ks < 4; ++ks) {
            #pragma unroll
            for (int n = 0; n < 8; ++n) {
                bf16x8 bfw = *(const bf16x8*)&fW1[((ks * 8 + n) * 64 + l) * 8];
                acc1[n] = __builtin_amdgcn_mfma_f32_16x16x32_bf16(a2[ks], bfw, acc1[n], 0, 0, 0);
            }
        }
        // g1 -> bounce (overwrite; DS ops are wave-ordered)
        #pragma unroll
        for (int n = 0; n < 8; ++n) {
            #pragma unroll
            for (int r = 0; r < 4; ++r) {
                float g = fmaxf(acc1[n][r] + b1v[n], 0.f);
                int row = lg * 4 + r;
                int col2 = (n * 16 + lr) * 2;
                *(unsigned short*)((char*)bw + row * 256 + (col2 ^ ((row & 7) << 4))) = f2bf(g);
            }
        }
        __builtin_amdgcn_s_waitcnt(0xc07f);  // lgkmcnt(0): g1-bounce visible

        // ---- layer 3: g2 = relu(g1 @ W2 + b2) ----
        bf16x8 a3[4];
        #pragma unroll
        for (int ks = 0; ks < 4; ++ks) {
            int roff = lr * 256 + ((ks * 64 + lg * 16) ^ ((lr & 7) << 4));
            a3[ks] = *(const bf16x8*)((const char*)bw + roff);
        }
        f32x4 acc2[4];
        #pragma unroll
        for (int n = 0; n < 4; ++n) acc2[n] = (f32x4){0.f, 0.f, 0.f, 0.f};
        #pragma unroll
        for (int ks = 0; ks < 4; ++ks) {
            #pragma unroll
            for (int n = 0; n < 4; ++n) {
                bf16x8 bfw = *(const bf16x8*)&fW2[((ks * 4 + n) * 64 + l) * 8];
                acc2[n] = __builtin_amdgcn_mfma_f32_16x16x32_bf16(a3[ks], bfw, acc2[n], 0, 0, 0);
            }
        }

        // ---- layer 4: dot w_eff, 16-lane reduce, sigmoid, store ----
        float p0 = 0.f, p1 = 0.f, p2 = 0.f, p3 = 0.f;
        #pragma unroll
        for (int n = 0; n < 4; ++n) {
            p0 += fmaxf(acc2[n][0] + b2v[n], 0.f) * wev[n];
            p1 += fmaxf(acc2[n][1] + b2v[n], 0.f) * wev[n];
            p2 += fmaxf(acc2[n][2] + b2v[n], 0.f) * wev[n];
            p3 += fmaxf(acc2[n][3] + b2v[n], 0.f) * wev[n];
        }
        #pragma unroll
        for (int m = 1; m < 16; m <<= 1) {
            p0 += __shfl_xor(p0, m);
            p1 += __shfl_xor(p1, m);
            p2 += __shfl_xor(p2, m);
            p3 += __shfl_xor(p3, m);
        }
        const size_t t = (size_t)blockIdx.x + (size_t)i * 256;
        const size_t s0 = t * 128 + (size_t)w * 16;
        float s0f = 1.f / (1.f + expf(-(p0 + bo)));
        float s1f = 1.f / (1.f + expf(-(p1 + bo)));
        float s2f = 1.f / (1.f + expf(-(p2 + bo)));
        float s3f = 1.f / (1.f + expf(-(p3 + bo)));
        if (lr < 4) {
            float v = (lr == 0) ? s0f : (lr == 1) ? s1f : (lr == 2) ? s2f : s3f;
            out[s0 + lg * 4 + lr] = v;
        }

        a0 += nextoff;
        a1 += nextoff;
    }
}

// ---------------- host launcher ----------------
extern "C" void kernel_launch(void* const* d_in, const int* in_sizes, int n_in,
                              void* d_out, int out_size, void* d_ws, size_t ws_size,
                              hipStream_t stream) {
    const float* combined = (const float*)d_in[0];
    const float* W_in  = (const float*)d_in[1];
    const float* b_in  = (const float*)d_in[2];
    const float* W1    = (const float*)d_in[3];
    const float* b1    = (const float*)d_in[4];
    const float* W2    = (const float*)d_in[5];
    const float* b2    = (const float*)d_in[6];
    const float* W_out = (const float*)d_in[7];
    const float* b_out = (const float*)d_in[8];
    float* out = (float*)d_out;

    char* ws = (char*)d_ws;
    unsigned short* fWin = (unsigned short*)(ws + WS_WIN);
    unsigned short* fW1  = (unsigned short*)(ws + WS_W1);
    unsigned short* fW2  = (unsigned short*)(ws + WS_W2);
    float* weff          = (float*)(ws + WS_WEFF);

    prep_kernel<<<(65536 + 16384 + 8192 + 64 + 255) / 256, 256, 0, stream>>>(
        W_in, W1, W2, W_out, fWin, fW1, fW2, weff);
    kA<<<256, 512, 0, stream>>>(combined, fWin, fW1, fW2, weff,
                                b_in, b1, b2, b_out, out);
}